// Round 4
// baseline (1159.731 us; speedup 1.0000x reference)
//
#include <hip/hip_runtime.h>
#include <hip/hip_bf16.h>

// LSAPPNP: h = relu(x@W1+b1); h2 = h@W2+b2; agg[r] += val*h2[c] over edges;
// out = log_softmax(0.1*h2 + agg, axis=1)
// N=100000, F_IN=500, HID=256, C=40, E~2.3M
//
// Round 10: edge-pipeline restructure. k_csr + k_spmm_lsm replaced by
// k_spmm_bucket: one block per 128-row bucket, LDS f32 accumulator
// (ds_add_f32), consuming bucket-grouped edges straight from k_split's
// output. Kills the row-ordering pass (~55MB traffic + 2 LDS-atomic
// passes + scan). MLP kept at the R8 version (measured best, 128.8us).

#define N_NODES 100000
#define F_IN    500
#define HID     256
#define C_OUT   40
#define ALPHA0  0.1f
#define H2STRIDE 64

#define RPB     128                           // rows per bucket
#define NBUCK   ((N_NODES + RPB - 1) / RPB)   // 782
#define NCH     320                           // edge chunks (hist/split blocks)
#define SCAN_M  (NBUCK * NCH)                 // 250240
#define SCAN_CHUNK 2048
#define NBS     ((SCAN_M + SCAN_CHUNK - 1) / SCAN_CHUNK)  // 123

typedef short short8 __attribute__((ext_vector_type(8)));
typedef float f32x4  __attribute__((ext_vector_type(4)));

__device__ __forceinline__ short f2bf(float f) {
  union { float f; unsigned u; } x; x.f = f;
  unsigned r = x.u + 0x7fffu + ((x.u >> 16) & 1u);  // RNE
  return (short)(r >> 16);
}
__device__ __forceinline__ float bf2f(short s) {
  union { unsigned u; float f; } x; x.u = ((unsigned)(unsigned short)s) << 16;
  return x.f;
}
// packed f32x2 -> bf16x2 (RNE), single VOP3
__device__ __forceinline__ unsigned cvtpk(float lo, float hi) {
  unsigned r;
  asm("v_cvt_pk_bf16_f32 %0, %1, %2" : "=v"(r) : "v"(lo), "v"(hi));
  return r;
}
// LDS-only barrier: drain DS ops, then raw s_barrier (no vmcnt drain).
__device__ __forceinline__ void lbar() {
  asm volatile("s_waitcnt lgkmcnt(0)" ::: "memory");
  __builtin_amdgcn_s_barrier();
}
// async global->LDS, 16B per lane; LDS dest = wave-uniform base + lane*16
__device__ __forceinline__ void gll16(const float* g, const char* l) {
  __builtin_amdgcn_global_load_lds(
      (const __attribute__((address_space(1))) void*)g,
      (__attribute__((address_space(3))) void*)l, 16, 0, 0);
}

// ---- K0: pack W1 -> W1S [16 kchunks][256 n][32 k] bf16; W2 -> W2T [48 n][256 k]
__global__ __launch_bounds__(256) void k_pack_weights(
    const float* __restrict__ W1, const float* __restrict__ W2,
    short* __restrict__ W1S, short* __restrict__ W2T)
{
  int i = blockIdx.x * 256 + threadIdx.x;
  if (i < 16*256*32) {
    int kc  = i >> 13;
    int idx = i & 8191;
    int n   = idx >> 5;
    int kk  = idx & 31;
    int k   = kc*32 + kk;
    float v = (k < F_IN) ? W1[k*HID + n] : 0.f;
    W1S[i] = f2bf(v);
  } else {
    int j = i - 16*256*32;
    if (j < 48*256) {
      int n = j >> 8;
      int k = j & 255;
      float v = (n < C_OUT) ? W2[k*C_OUT + n] : 0.f;
      W2T[j] = f2bf(v);
    }
  }
}

// ---- K1: fused MLP (R8 structure: gll f32 staging, counted vmcnt, no full
// syncthreads in K loop). 512 thr = 8 waves (2 row x 4 col), tile 128x256.
__global__ __launch_bounds__(512, 4) void k_fused_mlp(
    const float* __restrict__ x, const float* __restrict__ b1v,
    const float* __restrict__ b2v,
    const short* __restrict__ W1S, const short* __restrict__ W2T,
    short* __restrict__ h2b)
{
  __shared__ __align__(16) char smem[65536];
  short (*Hl)[256] = (short(*)[256])smem;   // post-loop overlay, 64KB

  const int tid  = threadIdx.x;
  const int w    = tid >> 6;
  const int lane = tid & 63;
  const int lr   = lane & 15;
  const int quad = lane >> 4;
  const int wr   = w >> 2;      // 0..1 row-wave
  const int wc   = w & 3;       // 0..3 col-wave
  const int row0 = blockIdx.x * 128;

  const int s_rl0 = (w*2)*8 + (lane>>3);
  const int s_rl1 = (w*2+1)*8 + (lane>>3);
  const int ksw   = ((lane&7) ^ ((lane>>3)&7)) * 4;
  const float* gp0 = x + (size_t)min(row0 + s_rl0, N_NODES-1) * F_IN;
  const float* gp1 = x + (size_t)min(row0 + s_rl1, N_NODES-1) * F_IN;
  const char* l0 = smem + (w*2)*1024;       // + buf*16384
  const char* l1 = smem + (w*2+1)*1024;

  f32x4 acc[4][4] = {};

  #pragma unroll
  for (int p = 0; p < 2; ++p) {
    int kb = p*32 + ksw;
    const float* a0 = (kb + 4 <= F_IN) ? gp0 + kb : x;
    const float* a1 = (kb + 4 <= F_IN) ? gp1 + kb : x;
    gll16(a0, l0 + p*16384);
    gll16(a1, l1 + p*16384);
  }

  const short* bbase = W1S + (wc*64 + lr)*32 + quad*8;
  const int m2 = lr & 7;

  #pragma unroll
  for (int kc = 0; kc < 16; ++kc) {
    short8 bf4[4];
    #pragma unroll
    for (int t = 0; t < 4; ++t)
      bf4[t] = *(const short8*)(bbase + kc*8192 + t*16*32);
    __builtin_amdgcn_sched_barrier(0);

    if (kc < 14) {
      int kb = (kc+2)*32 + ksw;
      const float* a0 = (kb + 4 <= F_IN) ? gp0 + kb : x;
      const float* a1 = (kb + 4 <= F_IN) ? gp1 + kb : x;
      gll16(a0, l0 + ((kc+2)&3)*16384);
      gll16(a1, l1 + ((kc+2)&3)*16384);
      __builtin_amdgcn_sched_barrier(0);
      asm volatile("s_waitcnt vmcnt(8)" ::: "memory");
    } else if (kc == 14) {
      asm volatile("s_waitcnt vmcnt(6)" ::: "memory");
    } else {
      asm volatile("s_waitcnt vmcnt(4)" ::: "memory");
    }
    __builtin_amdgcn_s_barrier();

    const char* Abase = smem + (kc & 3)*16384;
    short8 af[4];
    #pragma unroll
    for (int t = 0; t < 4; ++t) {
      int rl = wr*64 + t*16 + lr;
      f32x4 u0 = *(const f32x4*)(Abase + rl*128 + (((quad*2  ) ^ m2) << 4));
      f32x4 u1 = *(const f32x4*)(Abase + rl*128 + (((quad*2+1) ^ m2) << 4));
      union { unsigned u[4]; short8 s; } pk;
      pk.u[0] = cvtpk(u0[0], u0[1]);
      pk.u[1] = cvtpk(u0[2], u0[3]);
      pk.u[2] = cvtpk(u1[0], u1[1]);
      pk.u[3] = cvtpk(u1[2], u1[3]);
      af[t] = pk.s;
    }

    #pragma unroll
    for (int rt = 0; rt < 4; ++rt)
      #pragma unroll
      for (int ct = 0; ct < 4; ++ct)
        acc[rt][ct] = __builtin_amdgcn_mfma_f32_16x16x32_bf16(af[rt], bf4[ct], acc[rt][ct], 0, 0, 0);
  }
  lbar();

  #pragma unroll
  for (int ct = 0; ct < 4; ++ct) {
    int col = wc*64 + ct*16 + lr;
    int cg = col >> 3, ci = col & 7;
    float bias = b1v[col];
    #pragma unroll
    for (int rt = 0; rt < 4; ++rt) {
      #pragma unroll
      for (int r = 0; r < 4; ++r) {
        int row = wr*64 + rt*16 + quad*4 + r;
        float v = fmaxf(acc[rt][ct][r] + bias, 0.f);
        Hl[row][((cg ^ (row & 31)) << 3) | ci] = f2bf(v);
      }
    }
  }
  lbar();

  f32x4 acc2[3] = {};
  const int arow = w*16 + lr;
  #pragma unroll
  for (int kc2 = 0; kc2 < 8; ++kc2) {
    int gg = kc2*4 + quad;
    short8 a2 = *(const short8*)&Hl[arow][(gg ^ (arow & 31)) << 3];
    #pragma unroll
    for (int nt = 0; nt < 3; ++nt) {
      short8 b2 = *(const short8*)(W2T + (nt*16 + lr)*256 + kc2*32 + quad*8);
      acc2[nt] = __builtin_amdgcn_mfma_f32_16x16x32_bf16(a2, b2, acc2[nt], 0, 0, 0);
    }
  }

  #pragma unroll
  for (int nt = 0; nt < 3; ++nt) {
    int col = nt*16 + lr;
    float bias = (col < C_OUT) ? b2v[col] : 0.f;
    #pragma unroll
    for (int r = 0; r < 4; ++r) {
      int row = row0 + w*16 + quad*4 + r;
      if (row < N_NODES) {
        float v = (col < C_OUT) ? (acc2[nt][r] + bias) : 0.f;
        h2b[(long)row * H2STRIDE + col] = f2bf(v);
      }
    }
  }
  {
    int col = 48 + lr;
    #pragma unroll
    for (int r = 0; r < 4; ++r) {
      int row = row0 + w*16 + quad*4 + r;
      if (row < N_NODES) h2b[(long)row * H2STRIDE + col] = 0;
    }
  }
}

// ---- K2: per-chunk LDS histogram of buckets (row>>7). offs[b*NCH + c] = count
__global__ __launch_bounds__(256) void k_hist2(
    const int* __restrict__ erow, int* __restrict__ offs, int E, int CH)
{
  __shared__ int h[NBUCK];
  int tid = threadIdx.x, c = blockIdx.x;
  for (int b = tid; b < NBUCK; b += 256) h[b] = 0;
  __syncthreads();
  int e0 = c * CH, e1 = min(E, e0 + CH);
  for (int e = e0 + tid; e < e1; e += 256)
    atomicAdd(&h[erow[e] >> 7], 1);
  __syncthreads();
  for (int b = tid; b < NBUCK; b += 256) offs[b * NCH + c] = h[b];
}

// ---- K3a: scan phase 1 — 2048-elem chunks, in-place exclusive scan + sums
__global__ __launch_bounds__(256) void k_scan1(
    int* __restrict__ offs, int* __restrict__ bsums)
{
  __shared__ int sh[256];
  int tid = threadIdx.x;
  int base = blockIdx.x * SCAN_CHUNK + tid * 8;
  int d[8];
  #pragma unroll
  for (int k = 0; k < 8; ++k)
    d[k] = (base + k < SCAN_M) ? offs[base + k] : 0;
  int s = 0;
  #pragma unroll
  for (int k = 0; k < 8; ++k) s += d[k];
  sh[tid] = s;
  __syncthreads();
  for (int o = 1; o < 256; o <<= 1) {
    int v = (tid >= o) ? sh[tid - o] : 0;
    __syncthreads();
    if (tid >= o) sh[tid] += v;
    __syncthreads();
  }
  int run = sh[tid] - s;
  #pragma unroll
  for (int k = 0; k < 8; ++k) {
    if (base + k < SCAN_M) offs[base + k] = run;
    run += d[k];
  }
  if (tid == 255) bsums[blockIdx.x] = sh[255];
}

// ---- K3b: scan phase 2 — exclusive scan of NBS block sums (single block)
__global__ __launch_bounds__(256) void k_scan2(int* __restrict__ bsums) {
  __shared__ int sh[256];
  int tid = threadIdx.x;
  int v = (tid < NBS) ? bsums[tid] : 0;
  sh[tid] = v;
  __syncthreads();
  for (int o = 1; o < 256; o <<= 1) {
    int u = (tid >= o) ? sh[tid - o] : 0;
    __syncthreads();
    if (tid >= o) sh[tid] += u;
    __syncthreads();
  }
  if (tid < NBS) bsums[tid] = sh[tid] - v;
}

// ---- K3c: scan phase 3 — add block offsets
__global__ __launch_bounds__(256) void k_scan3(
    int* __restrict__ offs, const int* __restrict__ bsums)
{
  int i = blockIdx.x * 256 + threadIdx.x;
  if (i < SCAN_M) offs[i] += bsums[i >> 11];
}

// ---- K4: split edges into bucket-grouped order (LDS cursors, no dev atomics).
// sorted[pos] = { col | rowlow<<17 , val }
__global__ __launch_bounds__(256) void k_split(
    const int* __restrict__ erow, const int* __restrict__ ecol,
    const float* __restrict__ eval, const int* __restrict__ offs,
    int2* __restrict__ sorted, int E, int CH)
{
  __shared__ int cur[NBUCK];
  int tid = threadIdx.x, c = blockIdx.x;
  for (int b = tid; b < NBUCK; b += 256) cur[b] = offs[b * NCH + c];
  __syncthreads();
  int e0 = c * CH, e1 = min(E, e0 + CH);
  for (int e = e0 + tid; e < e1; e += 256) {
    int r = erow[e];
    int b = r >> 7;
    int pos = atomicAdd(&cur[b], 1);
    int2 cv;
    cv.x = ecol[e] | ((r & 127) << 17);
    cv.y = __float_as_int(eval[e]);
    sorted[pos] = cv;
  }
}

// ---- K5: bucket SpMM + fused log_softmax. One block per bucket (4 waves).
// LDS f32 accumulator [128][40]; edges consumed in bucket-grouped order
// (k_split output) — no row-ordering pass needed. Each wave: pull 64 edge
// records coalesced, broadcast via shfl, gather h2b line (64 lanes, cols
// 40..63 are zero), ds_add_f32 into accL. 8-deep load pipelining.
__global__ __launch_bounds__(256) void k_spmm_bucket(
    const int* __restrict__ offs, const int2* __restrict__ sorted,
    const short* __restrict__ h2b, float* __restrict__ out, int E)
{
  __shared__ float accL[RPB][C_OUT];   // 20480 B
  int tid = threadIdx.x, b = blockIdx.x;
  int lane = tid & 63, w = tid >> 6;
  int start = offs[b * NCH];
  int end   = (b + 1 < NBUCK) ? offs[(b + 1) * NCH] : E;

  for (int i = tid; i < RPB * C_OUT; i += 256) ((float*)accL)[i] = 0.f;
  __syncthreads();

  for (int base = start + w*64; base < end; base += 256) {
    int rem = end - base;
    int2 cv;
    cv.x = 0; cv.y = 0;
    if (lane < rem) cv = sorted[base + lane];
    if (rem >= 64) {
      for (int i = 0; i < 64; i += 8) {
        int rl[8]; float vv[8], gg[8];
        #pragma unroll
        for (int j = 0; j < 8; ++j) {
          int cx = __shfl(cv.x, i + j);
          int vy = __shfl(cv.y, i + j);
          int c  = cx & 0x1FFFF;
          rl[j] = ((unsigned)cx) >> 17;
          vv[j] = __int_as_float(vy);
          gg[j] = bf2f(h2b[(size_t)c * H2STRIDE + lane]);
        }
        if (lane < C_OUT) {
          #pragma unroll
          for (int j = 0; j < 8; ++j)
            atomicAdd(&accL[rl[j]][lane], vv[j] * gg[j]);
        }
      }
    } else {
      for (int i = 0; i < rem; ++i) {
        int cx = __shfl(cv.x, i);
        int vy = __shfl(cv.y, i);
        int c  = cx & 0x1FFFF;
        int rl = ((unsigned)cx) >> 17;
        float g = bf2f(h2b[(size_t)c * H2STRIDE + lane]);
        if (lane < C_OUT)
          atomicAdd(&accL[rl][lane], __int_as_float(vy) * g);
      }
    }
  }
  __syncthreads();

  // epilogue: wave w handles rows w*32 .. w*32+31 of the bucket
  for (int rr = 0; rr < 32; ++rr) {
    int r = w*32 + rr;
    int row = b * RPB + r;
    if (row >= N_NODES) continue;
    float a = -INFINITY;
    if (lane < C_OUT)
      a = accL[r][lane] + ALPHA0 * bf2f(h2b[(size_t)row * H2STRIDE + lane]);
    float m = a;
    #pragma unroll
    for (int o = 32; o > 0; o >>= 1) m = fmaxf(m, __shfl_xor(m, o));
    float ev = (lane < C_OUT) ? __expf(a - m) : 0.f;
    float s = ev;
    #pragma unroll
    for (int o = 32; o > 0; o >>= 1) s += __shfl_xor(s, o);
    if (lane < C_OUT) out[(long)row * C_OUT + lane] = a - m - __logf(s);
  }
}

extern "C" void kernel_launch(void* const* d_in, const int* in_sizes, int n_in,
                              void* d_out, int out_size, void* d_ws, size_t ws_size,
                              hipStream_t stream) {
  const float* x    = (const float*)d_in[0];
  const float* W1   = (const float*)d_in[1];
  const float* b1   = (const float*)d_in[2];
  const float* W2   = (const float*)d_in[3];
  const float* b2   = (const float*)d_in[4];
  const int*   erow = (const int*)d_in[5];
  const int*   ecol = (const int*)d_in[6];
  const float* eval = (const float*)d_in[7];
  const int E  = in_sizes[5];
  const int CH = (E + NCH - 1) / NCH;

  // ws: h2b 12.8MB | W1S 256KB | W2T 24KB | offs ~1MB | bsums 1KB | sorted E*8B
  char* p = (char*)d_ws;
  short* h2b      = (short*)p;  p += (size_t)N_NODES * H2STRIDE * 2;
  short* W1S      = (short*)p;  p += (size_t)16*256*32 * 2;
  short* W2T      = (short*)p;  p += (size_t)48*256 * 2;
  int*   offs     = (int*)p;    p += (size_t)SCAN_M * 4;
  int*   bsums    = (int*)p;    p += 256 * 4;
  int2*  sorted   = (int2*)p;
  float* out = (float*)d_out;

  k_pack_weights<<<(16*256*32 + 48*256 + 255)/256, 256, 0, stream>>>(W1, W2, W1S, W2T);
  k_fused_mlp<<<(N_NODES + 127)/128, 512, 0, stream>>>(x, b1, b2, W1S, W2T, h2b);
  k_hist2<<<NCH, 256, 0, stream>>>(erow, offs, E, CH);
  k_scan1<<<NBS, 256, 0, stream>>>(offs, bsums);
  k_scan2<<<1, 256, 0, stream>>>(bsums);
  k_scan3<<<(SCAN_M + 255)/256, 256, 0, stream>>>(offs, bsums);
  k_split<<<NCH, 256, 0, stream>>>(erow, ecol, eval, offs, sorted, E, CH);
  k_spmm_bucket<<<NBUCK, 256, 0, stream>>>(offs, sorted, h2b, out, E);
}

// Round 5
// 730.298 us; speedup vs baseline: 1.5880x; 1.5880x over previous
//
#include <hip/hip_runtime.h>
#include <hip/hip_bf16.h>

// LSAPPNP: h = relu(x@W1+b1); h2 = h@W2+b2; agg[r] += val*h2[c] over edges;
// out = log_softmax(0.1*h2 + agg, axis=1)
// N=100000, F_IN=500, HID=256, C=40, E~2.3M
//
// Round 11: direct row-sort. R10 revealed the old bucket machinery
// (hist2+scan250K+split, 320-block grids) cost ~290us and csr+spmm only
// ~126us. Replace hist2/scan/split/csr with: global-atomic row histogram
// (23 avg per counter, L2-resident 400KB) -> 100K scan -> one-pass
// atomic-cursor scatter directly into row order. Wave-per-row SpMM
// restored (proven). MLP kept at R8 version (128.8us measured).

#define N_NODES 100000
#define F_IN    500
#define HID     256
#define C_OUT   40
#define ALPHA0  0.1f
#define H2STRIDE 64

#define SCAN_CHUNK 2048
#define NBS_R   ((N_NODES + SCAN_CHUNK - 1) / SCAN_CHUNK)   // 49

typedef short short8 __attribute__((ext_vector_type(8)));
typedef float f32x4  __attribute__((ext_vector_type(4)));

__device__ __forceinline__ short f2bf(float f) {
  union { float f; unsigned u; } x; x.f = f;
  unsigned r = x.u + 0x7fffu + ((x.u >> 16) & 1u);  // RNE
  return (short)(r >> 16);
}
__device__ __forceinline__ float bf2f(short s) {
  union { unsigned u; float f; } x; x.u = ((unsigned)(unsigned short)s) << 16;
  return x.f;
}
// packed f32x2 -> bf16x2 (RNE), single VOP3
__device__ __forceinline__ unsigned cvtpk(float lo, float hi) {
  unsigned r;
  asm("v_cvt_pk_bf16_f32 %0, %1, %2" : "=v"(r) : "v"(lo), "v"(hi));
  return r;
}
// LDS-only barrier: drain DS ops, then raw s_barrier (no vmcnt drain).
__device__ __forceinline__ void lbar() {
  asm volatile("s_waitcnt lgkmcnt(0)" ::: "memory");
  __builtin_amdgcn_s_barrier();
}
// async global->LDS, 16B per lane; LDS dest = wave-uniform base + lane*16
__device__ __forceinline__ void gll16(const float* g, const char* l) {
  __builtin_amdgcn_global_load_lds(
      (const __attribute__((address_space(1))) void*)g,
      (__attribute__((address_space(3))) void*)l, 16, 0, 0);
}

// ---- K0: pack W1 -> W1S [16 kc][256 n][32 k] bf16; W2 -> W2T [48 n][256 k];
//          zero the row-count array (fused to save a dispatch).
__global__ __launch_bounds__(256) void k_pack_weights(
    const float* __restrict__ W1, const float* __restrict__ W2,
    short* __restrict__ W1S, short* __restrict__ W2T,
    int* __restrict__ rcnt)
{
  int i = blockIdx.x * 256 + threadIdx.x;
  if (i < 16*256*32) {
    int kc  = i >> 13;
    int idx = i & 8191;
    int n   = idx >> 5;
    int kk  = idx & 31;
    int k   = kc*32 + kk;
    float v = (k < F_IN) ? W1[k*HID + n] : 0.f;
    W1S[i] = f2bf(v);
  } else if (i < 16*256*32 + 48*256) {
    int j = i - 16*256*32;
    int n = j >> 8;
    int k = j & 255;
    float v = (n < C_OUT) ? W2[k*C_OUT + n] : 0.f;
    W2T[j] = f2bf(v);
  } else {
    int j = i - (16*256*32 + 48*256);
    if (j <= N_NODES) rcnt[j] = 0;
  }
}

// ---- K1: fused MLP (R8 structure: gll f32 staging, counted vmcnt, no full
// syncthreads in K loop). 512 thr = 8 waves (2 row x 4 col), tile 128x256.
__global__ __launch_bounds__(512, 4) void k_fused_mlp(
    const float* __restrict__ x, const float* __restrict__ b1v,
    const float* __restrict__ b2v,
    const short* __restrict__ W1S, const short* __restrict__ W2T,
    short* __restrict__ h2b)
{
  __shared__ __align__(16) char smem[65536];
  short (*Hl)[256] = (short(*)[256])smem;   // post-loop overlay, 64KB

  const int tid  = threadIdx.x;
  const int w    = tid >> 6;
  const int lane = tid & 63;
  const int lr   = lane & 15;
  const int quad = lane >> 4;
  const int wr   = w >> 2;      // 0..1 row-wave
  const int wc   = w & 3;       // 0..3 col-wave
  const int row0 = blockIdx.x * 128;

  const int s_rl0 = (w*2)*8 + (lane>>3);
  const int s_rl1 = (w*2+1)*8 + (lane>>3);
  const int ksw   = ((lane&7) ^ ((lane>>3)&7)) * 4;
  const float* gp0 = x + (size_t)min(row0 + s_rl0, N_NODES-1) * F_IN;
  const float* gp1 = x + (size_t)min(row0 + s_rl1, N_NODES-1) * F_IN;
  const char* l0 = smem + (w*2)*1024;       // + buf*16384
  const char* l1 = smem + (w*2+1)*1024;

  f32x4 acc[4][4] = {};

  #pragma unroll
  for (int p = 0; p < 2; ++p) {
    int kb = p*32 + ksw;
    const float* a0 = (kb + 4 <= F_IN) ? gp0 + kb : x;
    const float* a1 = (kb + 4 <= F_IN) ? gp1 + kb : x;
    gll16(a0, l0 + p*16384);
    gll16(a1, l1 + p*16384);
  }

  const short* bbase = W1S + (wc*64 + lr)*32 + quad*8;
  const int m2 = lr & 7;

  #pragma unroll
  for (int kc = 0; kc < 16; ++kc) {
    short8 bf4[4];
    #pragma unroll
    for (int t = 0; t < 4; ++t)
      bf4[t] = *(const short8*)(bbase + kc*8192 + t*16*32);
    __builtin_amdgcn_sched_barrier(0);

    if (kc < 14) {
      int kb = (kc+2)*32 + ksw;
      const float* a0 = (kb + 4 <= F_IN) ? gp0 + kb : x;
      const float* a1 = (kb + 4 <= F_IN) ? gp1 + kb : x;
      gll16(a0, l0 + ((kc+2)&3)*16384);
      gll16(a1, l1 + ((kc+2)&3)*16384);
      __builtin_amdgcn_sched_barrier(0);
      asm volatile("s_waitcnt vmcnt(8)" ::: "memory");
    } else if (kc == 14) {
      asm volatile("s_waitcnt vmcnt(6)" ::: "memory");
    } else {
      asm volatile("s_waitcnt vmcnt(4)" ::: "memory");
    }
    __builtin_amdgcn_s_barrier();

    const char* Abase = smem + (kc & 3)*16384;
    short8 af[4];
    #pragma unroll
    for (int t = 0; t < 4; ++t) {
      int rl = wr*64 + t*16 + lr;
      f32x4 u0 = *(const f32x4*)(Abase + rl*128 + (((quad*2  ) ^ m2) << 4));
      f32x4 u1 = *(const f32x4*)(Abase + rl*128 + (((quad*2+1) ^ m2) << 4));
      union { unsigned u[4]; short8 s; } pk;
      pk.u[0] = cvtpk(u0[0], u0[1]);
      pk.u[1] = cvtpk(u0[2], u0[3]);
      pk.u[2] = cvtpk(u1[0], u1[1]);
      pk.u[3] = cvtpk(u1[2], u1[3]);
      af[t] = pk.s;
    }

    #pragma unroll
    for (int rt = 0; rt < 4; ++rt)
      #pragma unroll
      for (int ct = 0; ct < 4; ++ct)
        acc[rt][ct] = __builtin_amdgcn_mfma_f32_16x16x32_bf16(af[rt], bf4[ct], acc[rt][ct], 0, 0, 0);
  }
  lbar();

  #pragma unroll
  for (int ct = 0; ct < 4; ++ct) {
    int col = wc*64 + ct*16 + lr;
    int cg = col >> 3, ci = col & 7;
    float bias = b1v[col];
    #pragma unroll
    for (int rt = 0; rt < 4; ++rt) {
      #pragma unroll
      for (int r = 0; r < 4; ++r) {
        int row = wr*64 + rt*16 + quad*4 + r;
        float v = fmaxf(acc[rt][ct][r] + bias, 0.f);
        Hl[row][((cg ^ (row & 31)) << 3) | ci] = f2bf(v);
      }
    }
  }
  lbar();

  f32x4 acc2[3] = {};
  const int arow = w*16 + lr;
  #pragma unroll
  for (int kc2 = 0; kc2 < 8; ++kc2) {
    int gg = kc2*4 + quad;
    short8 a2 = *(const short8*)&Hl[arow][(gg ^ (arow & 31)) << 3];
    #pragma unroll
    for (int nt = 0; nt < 3; ++nt) {
      short8 b2 = *(const short8*)(W2T + (nt*16 + lr)*256 + kc2*32 + quad*8);
      acc2[nt] = __builtin_amdgcn_mfma_f32_16x16x32_bf16(a2, b2, acc2[nt], 0, 0, 0);
    }
  }

  #pragma unroll
  for (int nt = 0; nt < 3; ++nt) {
    int col = nt*16 + lr;
    float bias = (col < C_OUT) ? b2v[col] : 0.f;
    #pragma unroll
    for (int r = 0; r < 4; ++r) {
      int row = row0 + w*16 + quad*4 + r;
      if (row < N_NODES) {
        float v = (col < C_OUT) ? (acc2[nt][r] + bias) : 0.f;
        h2b[(long)row * H2STRIDE + col] = f2bf(v);
      }
    }
  }
  {
    int col = 48 + lr;
    #pragma unroll
    for (int r = 0; r < 4; ++r) {
      int row = row0 + w*16 + quad*4 + r;
      if (row < N_NODES) h2b[(long)row * H2STRIDE + col] = 0;
    }
  }
}

// ---- K2: row histogram via device atomics (counter array L2-resident,
// ~23 edges/row avg -> negligible contention). Grid-stride, 2048 blocks.
__global__ __launch_bounds__(256) void k_hist_rows(
    const int* __restrict__ erow, int* __restrict__ rcnt, int E)
{
  int i = blockIdx.x * 256 + threadIdx.x;
  int stride = gridDim.x * 256;
  for (int e = i; e < E; e += stride)
    atomicAdd(&rcnt[erow[e]], 1);
}

// ---- K3a: scan phase 1 — 2048-elem chunks over N_NODES, in-place + sums
__global__ __launch_bounds__(256) void k_scan1(
    int* __restrict__ offs, int* __restrict__ bsums)
{
  __shared__ int sh[256];
  int tid = threadIdx.x;
  int base = blockIdx.x * SCAN_CHUNK + tid * 8;
  int d[8];
  #pragma unroll
  for (int k = 0; k < 8; ++k)
    d[k] = (base + k < N_NODES) ? offs[base + k] : 0;
  int s = 0;
  #pragma unroll
  for (int k = 0; k < 8; ++k) s += d[k];
  sh[tid] = s;
  __syncthreads();
  for (int o = 1; o < 256; o <<= 1) {
    int v = (tid >= o) ? sh[tid - o] : 0;
    __syncthreads();
    if (tid >= o) sh[tid] += v;
    __syncthreads();
  }
  int run = sh[tid] - s;
  #pragma unroll
  for (int k = 0; k < 8; ++k) {
    if (base + k < N_NODES) offs[base + k] = run;
    run += d[k];
  }
  if (tid == 255) bsums[blockIdx.x] = sh[255];
}

// ---- K3b: scan phase 2 — exclusive scan of NBS_R block sums (single block)
__global__ __launch_bounds__(256) void k_scan2(int* __restrict__ bsums) {
  __shared__ int sh[256];
  int tid = threadIdx.x;
  int v = (tid < NBS_R) ? bsums[tid] : 0;
  sh[tid] = v;
  __syncthreads();
  for (int o = 1; o < 256; o <<= 1) {
    int u = (tid >= o) ? sh[tid - o] : 0;
    __syncthreads();
    if (tid >= o) sh[tid] += u;
    __syncthreads();
  }
  if (tid < NBS_R) bsums[tid] = sh[tid] - v;
}

// ---- K3c: scan phase 3 — add block offsets; clone cursors; close row_offs
__global__ __launch_bounds__(256) void k_scan3(
    int* __restrict__ offs, const int* __restrict__ bsums,
    int* __restrict__ cur, int E)
{
  int i = blockIdx.x * 256 + threadIdx.x;
  if (i < N_NODES) {
    int v = offs[i] + bsums[i >> 11];
    offs[i] = v;
    cur[i]  = v;
  }
  if (i == 0) offs[N_NODES] = E;
}

// ---- K4: one-pass scatter into row-sorted order. pos = cursor[row]++.
// sorted2[pos] = { col, val }. Row-internal order arbitrary (sum commutes).
__global__ __launch_bounds__(256) void k_scatter(
    const int* __restrict__ erow, const int* __restrict__ ecol,
    const float* __restrict__ eval, int* __restrict__ cur,
    int2* __restrict__ sorted2, int E)
{
  int i = blockIdx.x * 256 + threadIdx.x;
  int stride = gridDim.x * 256;
  for (int e = i; e < E; e += stride) {
    int r = erow[e];
    int pos = atomicAdd(&cur[r], 1);
    int2 cv;
    cv.x = ecol[e];
    cv.y = __float_as_int(eval[e]);
    sorted2[pos] = cv;
  }
}

// ---- K5: wave-per-row gather SpMM + fused log_softmax (4 rows/block).
// h2b stride 64: each gather is one aligned 128B line, all 64 lanes active.
__global__ __launch_bounds__(256) void k_spmm_lsm(
    const int* __restrict__ row_offs, const int2* __restrict__ sorted2,
    const short* __restrict__ h2b, float* __restrict__ out)
{
  int row  = blockIdx.x * 4 + (threadIdx.x >> 6);
  int lane = threadIdx.x & 63;
  if (row >= N_NODES) return;

  float acc = ALPHA0 * bf2f(h2b[(long)row * H2STRIDE + lane]);  // 0 for lane>=40

  int e   = row_offs[row];
  int end = row_offs[row + 1];
  for (; e + 3 < end; e += 4) {
    int2 cv0 = sorted2[e];
    int2 cv1 = sorted2[e + 1];
    int2 cv2 = sorted2[e + 2];
    int2 cv3 = sorted2[e + 3];
    float g0 = bf2f(h2b[(size_t)cv0.x * H2STRIDE + lane]);
    float g1 = bf2f(h2b[(size_t)cv1.x * H2STRIDE + lane]);
    float g2 = bf2f(h2b[(size_t)cv2.x * H2STRIDE + lane]);
    float g3 = bf2f(h2b[(size_t)cv3.x * H2STRIDE + lane]);
    acc += __int_as_float(cv0.y) * g0;
    acc += __int_as_float(cv1.y) * g1;
    acc += __int_as_float(cv2.y) * g2;
    acc += __int_as_float(cv3.y) * g3;
  }
  for (; e < end; ++e) {
    int2 cv = sorted2[e];
    acc += __int_as_float(cv.y) * bf2f(h2b[(size_t)cv.x * H2STRIDE + lane]);
  }

  float m = (lane < C_OUT) ? acc : -INFINITY;
  #pragma unroll
  for (int o = 32; o > 0; o >>= 1) m = fmaxf(m, __shfl_xor(m, o));
  float ev = (lane < C_OUT) ? __expf(acc - m) : 0.f;
  float s = ev;
  #pragma unroll
  for (int o = 32; o > 0; o >>= 1) s += __shfl_xor(s, o);
  if (lane < C_OUT) out[(long)row * C_OUT + lane] = acc - m - __logf(s);
}

extern "C" void kernel_launch(void* const* d_in, const int* in_sizes, int n_in,
                              void* d_out, int out_size, void* d_ws, size_t ws_size,
                              hipStream_t stream) {
  const float* x    = (const float*)d_in[0];
  const float* W1   = (const float*)d_in[1];
  const float* b1   = (const float*)d_in[2];
  const float* W2   = (const float*)d_in[3];
  const float* b2   = (const float*)d_in[4];
  const int*   erow = (const int*)d_in[5];
  const int*   ecol = (const int*)d_in[6];
  const float* eval = (const float*)d_in[7];
  const int E  = in_sizes[5];

  // ws: h2b 12.8MB | W1S 256KB | W2T 24KB | row_offs 400KB | cursor 400KB |
  //     bsums 1KB | sorted2 E*8B  (~33 MB)
  char* p = (char*)d_ws;
  short* h2b      = (short*)p;  p += (size_t)N_NODES * H2STRIDE * 2;
  short* W1S      = (short*)p;  p += (size_t)16*256*32 * 2;
  short* W2T      = (short*)p;  p += (size_t)48*256 * 2;
  int*   row_offs = (int*)p;    p += (size_t)(N_NODES + 4) * 4;
  int*   cursor   = (int*)p;    p += (size_t)(N_NODES + 4) * 4;
  int*   bsums    = (int*)p;    p += 256 * 4;
  int2*  sorted2  = (int2*)p;
  float* out = (float*)d_out;

  const int pack_work = 16*256*32 + 48*256 + N_NODES + 1;
  k_pack_weights<<<(pack_work + 255)/256, 256, 0, stream>>>(W1, W2, W1S, W2T, row_offs);
  k_fused_mlp<<<(N_NODES + 127)/128, 512, 0, stream>>>(x, b1, b2, W1S, W2T, h2b);
  k_hist_rows<<<2048, 256, 0, stream>>>(erow, row_offs, E);
  k_scan1<<<NBS_R, 256, 0, stream>>>(row_offs, bsums);
  k_scan2<<<1, 256, 0, stream>>>(bsums);
  k_scan3<<<(N_NODES + 255)/256, 256, 0, stream>>>(row_offs, bsums, cursor, E);
  k_scatter<<<2048, 256, 0, stream>>>(erow, ecol, eval, cursor, sorted2, E);
  k_spmm_lsm<<<(N_NODES + 3)/4, 256, 0, stream>>>(row_offs, sorted2, h2b, out);
}